// Round 1
// baseline (2883.870 us; speedup 1.0000x reference)
//
#include <hip/hip_runtime.h>
#include <stdint.h>

#define RT 256
#define RTILE 4096
#define ROUNDS 48

// ============================ init ============================
__global__ void k_init_counters(int* counters){
  int t = threadIdx.x;
  counters[t] = 0;
  if (t == 7) counters[7] = 1;  // sentinel gate for round 0
}
__global__ void k_init_nodes(int* mask, int* mis, int* nb, int* mn, int N){
  int v = blockIdx.x*blockDim.x + threadIdx.x;
  if (v < N){ mask[v]=0; mis[v]=0; nb[v]=0; mn[v]=N; }
}
__global__ void k_zero_vals(float* vals, int E){
  int i = blockIdx.x*blockDim.x + threadIdx.x;
  if (i < E) vals[i]=0.f;
}

// ============================ rank (stable argsort of score) ============================
__global__ void k_score_key(const float* score, unsigned* keys, unsigned* pay, int N){
  int i = blockIdx.x*blockDim.x+threadIdx.x;
  if (i<N){
    unsigned b = __float_as_uint(score[i]);
    b ^= ((int)b < 0) ? 0xFFFFFFFFu : 0x80000000u;   // order-preserving float->uint
    keys[i]=b; pay[i]=(unsigned)i;
  }
}
__global__ void k_rank_build(const unsigned* pay, int* rank, int* minrank, int N){
  int p = blockIdx.x*blockDim.x+threadIdx.x;
  if (p<N){ int v = (int)pay[p]; rank[v]=p; minrank[v]=p; }
}

// ============================ radix sort (stable LSD, 8-bit digits) ============================
template<typename K>
__global__ void k_radix_hist(const K* __restrict__ keys, int n, int shift,
                             unsigned* __restrict__ ghist, int numBlocks){
  __shared__ unsigned h[256];
  int t=threadIdx.x, b=blockIdx.x;
  h[t]=0; __syncthreads();
  int base = b*RTILE;
  for (int j=t; j<RTILE; j+=RT){
    int i = base+j;
    if (i<n){
      unsigned d = (unsigned)((keys[i]>>shift)&(K)255);
      atomicAdd(&h[d],1u);
    }
  }
  __syncthreads();
  ghist[(size_t)t*numBlocks + b] = h[t];
}

template<typename K>
__global__ void k_radix_scatter(const K* __restrict__ keysIn, const unsigned* __restrict__ payIn,
                                K* __restrict__ keysOut, unsigned* __restrict__ payOut,
                                int n, int shift, const unsigned* __restrict__ gbase, int numBlocks){
  __shared__ unsigned carry[256];
  int t=threadIdx.x, b=blockIdx.x;
  carry[t]=0; __syncthreads();
  int lane = t&63, wave = t>>6;
  int base = b*RTILE;
  for (int r=0; r<RTILE/RT; ++r){
    int i = base + r*RT + t;
    bool valid = i<n;
    K k = valid ? keysIn[i] : (K)0;
    unsigned pay = valid ? payIn[i] : 0u;
    unsigned d = (unsigned)((k>>shift)&(K)255);
    unsigned off=0;
    // serialize 4 waves in order for a stable within-block rank
    for (int w=0; w<RT/64; ++w){
      if (wave==w){
        unsigned long long m = __ballot(valid);
        #pragma unroll
        for (int bit=0; bit<8; ++bit){
          unsigned long long bb = __ballot((d>>bit)&1u);
          m &= ((d>>bit)&1u) ? bb : ~bb;
        }
        int lr = __popcll(m & ((1ull<<lane)-1ull));
        unsigned cb = carry[d];
        off = cb + (unsigned)lr;
        if (valid && lr==0) carry[d] = cb + (unsigned)__popcll(m);  // unique leader per digit
      }
      __syncthreads();
    }
    if (valid){
      unsigned pos = gbase[(size_t)d*numBlocks + b] + off;
      keysOut[pos]=k; payOut[pos]=pay;
    }
  }
}

// single-block exclusive scan (in-place), for histograms / block sums
__global__ void k_scan_single(unsigned* data, int n, unsigned* total){
  __shared__ unsigned sh[1024];
  __shared__ unsigned carry;
  int t=threadIdx.x;
  if (t==0) carry=0;
  __syncthreads();
  for (int base=0; base<n; base+=4096){
    unsigned v[4]; unsigned s=0;
    int i0 = base + t*4;
    #pragma unroll
    for (int j=0;j<4;j++){ int i=i0+j; v[j] = (i<n)?data[i]:0u; s+=v[j]; }
    sh[t]=s; __syncthreads();
    for (int off=1; off<1024; off<<=1){
      unsigned x = (t>=off)? sh[t-off]:0u; __syncthreads();
      sh[t]+=x; __syncthreads();
    }
    unsigned excl = (t?sh[t-1]:0u) + carry;
    #pragma unroll
    for (int j=0;j<4;j++){ int i=i0+j; if(i<n){ unsigned o=v[j]; data[i]=excl; excl+=o; } }
    unsigned tot = sh[1023];
    __syncthreads();
    if (t==0) carry += tot;
    __syncthreads();
  }
  if (total && t==0) *total = carry;
}

// 3-kernel big exclusive scan
__global__ void k_scan_partials(const unsigned* __restrict__ in, unsigned* __restrict__ bsums, int n){
  __shared__ unsigned sh[256];
  int b=blockIdx.x, t=threadIdx.x;
  long base = (long)b*RTILE + (long)t*16;
  unsigned s=0;
  #pragma unroll
  for (int j=0;j<16;j++){ long i=base+j; if(i<n) s+=in[i]; }
  sh[t]=s; __syncthreads();
  for (int off=128; off>0; off>>=1){ if(t<off) sh[t]+=sh[t+off]; __syncthreads(); }
  if (t==0) bsums[b]=sh[0];
}
__global__ void k_scan_final(const unsigned* __restrict__ in, unsigned* __restrict__ out,
                             const unsigned* __restrict__ bsums, int n){
  __shared__ unsigned sh[256];
  int b=blockIdx.x, t=threadIdx.x;
  long base = (long)b*RTILE + (long)t*16;
  unsigned v[16]; unsigned s=0;
  #pragma unroll
  for (int j=0;j<16;j++){ long i=base+j; v[j]=(i<n)?in[i]:0u; s+=v[j]; }
  sh[t]=s; __syncthreads();
  for (int off=1; off<256; off<<=1){
    unsigned x=(t>=off)?sh[t-off]:0u; __syncthreads(); sh[t]+=x; __syncthreads();
  }
  unsigned run=(t?sh[t-1]:0u)+bsums[b];
  #pragma unroll
  for (int j=0;j<16;j++){ long i=base+j; if(i<n){ unsigned o=v[j]; out[i]=run; run+=o; } }
}

// ============================ MIS rounds (gated; replicate reference exactly) ============================
__global__ void k_mis_edge_min(const int* __restrict__ row, const int* __restrict__ col,
                               const int* __restrict__ minrank, int* __restrict__ mn,
                               int E, int N, const int* gate){
  if (*gate == 0) return;
  for (int e = blockIdx.x*blockDim.x+threadIdx.x; e < E; e += gridDim.x*blockDim.x){
    int v = minrank[row[e]];
    if (v < N) atomicMin(&mn[col[e]], v);
  }
}
__global__ void k_mis_node_update(const int* __restrict__ rank, int* __restrict__ minrank,
                                  int* __restrict__ mn, int* __restrict__ mis,
                                  const int* __restrict__ mask, int* __restrict__ maskA,
                                  int N, const int* gate){
  if (*gate==0) return;
  int v = blockIdx.x*blockDim.x+threadIdx.x;
  if (v<N){
    int mr = min(minrank[v], mn[v]);
    minrank[v]=mr;
    mn[v]=N;                       // re-init for next round
    int nm = (rank[v]==mr) & (mask[v]==0);
    if (nm) mis[v]=1;
    maskA[v] = mask[v] | nm;       // mask |= mis
  }
}
__global__ void k_mis_edge_prop(const int* __restrict__ row, const int* __restrict__ col,
                                const int* __restrict__ maskA, int* __restrict__ nb,
                                int E, const int* gate){
  if (*gate==0) return;
  for (int e = blockIdx.x*blockDim.x+threadIdx.x; e < E; e += gridDim.x*blockDim.x){
    if (maskA[row[e]]) nb[col[e]]=1;
  }
}
__global__ void k_mis_node_fin(const int* __restrict__ rank, int* __restrict__ minrank,
                               int* __restrict__ mask, const int* __restrict__ maskA,
                               int* __restrict__ nb, int N, int* cnt, const int* gate){
  if (*gate==0) return;
  int v = blockIdx.x*blockDim.x+threadIdx.x;
  int um = 0;
  if (v<N){
    int mk = maskA[v] | nb[v];
    mask[v]=mk; nb[v]=0;
    minrank[v] = mk ? N : rank[v];
    um = (mk==0);
  }
  unsigned long long bm = __ballot(um);
  if ((threadIdx.x&63)==0 && bm) atomicAdd(cnt, (int)__popcll(bm));
}

// ============================ clustering ============================
__global__ void k_cl_init(const int* rank, const int* mis, int* minrank, int* mn, int N){
  int v = blockIdx.x*blockDim.x+threadIdx.x;
  if (v<N){ minrank[v] = mis[v]? rank[v] : N; mn[v]=N; }
}
__global__ void k_cl_edge(const int* __restrict__ row, const int* __restrict__ col,
                          const int* __restrict__ minrank, int* __restrict__ mn, int E, int N){
  for (int e = blockIdx.x*blockDim.x+threadIdx.x; e < E; e += gridDim.x*blockDim.x){
    int x = minrank[row[e]];
    if (x < N) atomicMin(&mn[col[e]], x);
  }
}
__global__ void k_cl_fin(const int* minrank, int* mn, int N){
  int v = blockIdx.x*blockDim.x+threadIdx.x;
  if (v<N) mn[v] = min(mn[v], minrank[v]);
}
__global__ void k_copy_u32(const int* in, unsigned* out, int N){
  int v = blockIdx.x*blockDim.x+threadIdx.x;
  if (v<N) out[v]=(unsigned)in[v];
}
__global__ void k_cl_map(const int* rank, const int* mis, const unsigned* cidx,
                         int* map, int* rmax, int N){
  int v = blockIdx.x*blockDim.x+threadIdx.x;
  if (v<N && mis[v]){ map[rank[v]] = (int)cidx[v]; atomicMax(rmax, rank[v]); }
}
__global__ void k_cl_cluster(const int* mn, const int* map, const int* rmax, int* cluster, int N){
  int v = blockIdx.x*blockDim.x+threadIdx.x;
  if (v<N){
    int mr = mn[v];
    if (mr >= N) mr = *rmax;      // JAX OOB-gather clamp semantics for uncovered nodes
    cluster[v] = map[mr];
  }
}
__global__ void k_gather_x(const float4* __restrict__ x, float4* __restrict__ out,
                           const int* __restrict__ mis, const unsigned* __restrict__ cidx,
                           int N, int D4){
  int t = blockIdx.x*blockDim.x+threadIdx.x;
  int v = t / D4, q = t - v*D4;
  if (v<N && mis[v]) out[(size_t)cidx[v]*D4 + q] = x[(size_t)v*D4 + q];
}

// ============================ coarsened-edge aggregation ============================
__global__ void k_pair_key(const int* __restrict__ row, const int* __restrict__ col,
                           const int* __restrict__ cluster,
                           unsigned long long* __restrict__ keys, unsigned* __restrict__ pay, int E){
  int e = blockIdx.x*blockDim.x+threadIdx.x;
  if (e<E){
    unsigned a = (unsigned)cluster[row[e]], b=(unsigned)cluster[col[e]];
    keys[e] = ((unsigned long long)a<<17) | b;   // M <= N=100000 < 2^17
    pay[e]=(unsigned)e;
  }
}
__global__ void k_head_flags(const unsigned long long* __restrict__ keys, unsigned* flags, int E){
  int i = blockIdx.x*blockDim.x+threadIdx.x;
  if (i<E) flags[i] = (i==0) || (keys[i]!=keys[i-1]);
}
__global__ void k_acc_vals(const unsigned long long* __restrict__ keys, const unsigned* __restrict__ pay,
                           const unsigned* __restrict__ excl1, const float* __restrict__ attr,
                           float* __restrict__ vals, int E){
  int i = blockIdx.x*blockDim.x+threadIdx.x;
  if (i<E){
    int head = (i==0)||(keys[i]!=keys[i-1]);
    unsigned g = excl1[i] + (unsigned)head - 1u;   // group index of i
    atomicAdd(&vals[g], attr[pay[i]]);
  }
}
__global__ void k_keep_flags(const unsigned long long* __restrict__ keys, unsigned* flags, int E){
  int i = blockIdx.x*blockDim.x+threadIdx.x;
  if (i<E){
    int head=(i==0)||(keys[i]!=keys[i-1]);
    unsigned a=(unsigned)(keys[i]>>17), b=(unsigned)(keys[i]&0x1FFFFull);
    flags[i] = (head && (a!=b)) ? 1u : 0u;
  }
}
__global__ void k_write_edges(const unsigned long long* __restrict__ keys,
                              const unsigned* __restrict__ excl1, const unsigned* __restrict__ excl2,
                              const float* __restrict__ vals, float* __restrict__ out,
                              const int* __restrict__ counters, int E, int D){
  int i = blockIdx.x*blockDim.x+threadIdx.x;
  if (i<E){
    int head=(i==0)||(keys[i]!=keys[i-1]);
    unsigned a=(unsigned)(keys[i]>>17), b=(unsigned)(keys[i]&0x1FFFFull);
    if (head && a!=b){
      unsigned opos = excl2[i];
      int M = counters[1], Ep = counters[3];
      size_t off = (size_t)M*D;
      out[off + opos] = (float)a;
      out[off + (size_t)Ep + opos] = (float)b;
      out[off + 2*(size_t)Ep + opos] = vals[excl1[i]];  // head => group = excl1[i]
    }
  }
}
__global__ void k_write_nodes(const int* __restrict__ cluster, const int* __restrict__ mis,
                              const float* __restrict__ score, float* __restrict__ out,
                              const int* __restrict__ counters, int N, int D){
  int v = blockIdx.x*blockDim.x+threadIdx.x;
  if (v<N){
    int M=counters[1], Ep=counters[3];
    size_t off = (size_t)M*D + 3*(size_t)Ep;
    out[off + v] = (float)cluster[v];
    out[off + (size_t)N + v] = mis[v] ? 1.f : 0.f;
    out[off + 2*(size_t)N + v] = score[v];
  }
}

// ============================ host ============================
extern "C" void kernel_launch(void* const* d_in, const int* in_sizes, int n_in,
                              void* d_out, int out_size, void* d_ws, size_t ws_size,
                              hipStream_t stream){
  const float* x     = (const float*)d_in[0];
  const int*   ei    = (const int*)d_in[1];
  const float* attr  = (const float*)d_in[2];
  const float* score = (const float*)d_in[3];
  int N = in_sizes[3];
  int E = in_sizes[2];
  int D = in_sizes[0]/N;
  const int* row = ei;
  const int* col = ei + E;
  float* out = (float*)d_out;

  char* p = (char*)d_ws;
  auto alloc = [&](size_t bytes)->char*{ char* r=p; p += ((bytes+255)/256)*256; return r; };
  unsigned long long* keyA = (unsigned long long*)alloc((size_t)E*8);
  unsigned long long* keyB = (unsigned long long*)alloc((size_t)E*8);
  unsigned* payA  = (unsigned*)alloc((size_t)E*4);
  unsigned* payB  = (unsigned*)alloc((size_t)E*4);
  unsigned* scanA = (unsigned*)alloc((size_t)E*4);
  unsigned* scanB = (unsigned*)alloc((size_t)E*4);
  float*    vals  = (float*)alloc((size_t)E*4);
  int* rank   = (int*)alloc((size_t)N*4);
  int* minrank= (int*)alloc((size_t)N*4);
  int* mn     = (int*)alloc((size_t)N*4);
  int* mis    = (int*)alloc((size_t)N*4);
  int* mask   = (int*)alloc((size_t)N*4);
  int* maskA  = (int*)alloc((size_t)N*4);
  int* nbv    = (int*)alloc((size_t)N*4);
  int* map    = (int*)alloc((size_t)N*4);
  unsigned* cidx = (unsigned*)alloc((size_t)N*4);
  int* cluster= (int*)alloc((size_t)N*4);
  int* counters=(int*)alloc(256*4);
  int Be = (E + RTILE-1)/RTILE;
  int Bn = (N + RTILE-1)/RTILE;
  unsigned* ghist = (unsigned*)alloc((size_t)256*Be*4);
  unsigned* bsums = (unsigned*)alloc(4096*4);

  int nbN = (N+255)/256, nbE = (E+255)/256;
  int egrid = 2048;  // grid-stride edge kernels (cheap when gated off)

  k_init_counters<<<1,256,0,stream>>>(counters);
  k_init_nodes<<<nbN,256,0,stream>>>(mask,mis,nbv,mn,N);
  k_zero_vals<<<nbE,256,0,stream>>>(vals,E);

  // ---- rank = stable argsort(argsort(score)) via 4-pass LSD radix ----
  unsigned* ski = (unsigned*)keyA;
  unsigned* sko = (unsigned*)keyB;
  k_score_key<<<nbN,256,0,stream>>>(score, ski, payA, N);
  {
    unsigned *ki=ski,*ko=sko,*pi=payA,*po=payB;
    for (int pass=0; pass<4; ++pass){
      int shift = pass*8;
      k_radix_hist<unsigned><<<Bn,256,0,stream>>>(ki,N,shift,ghist,Bn);
      k_scan_single<<<1,1024,0,stream>>>(ghist,256*Bn,nullptr);
      k_radix_scatter<unsigned><<<Bn,256,0,stream>>>(ki,pi,ko,po,N,shift,ghist,Bn);
      unsigned* tk=ki; ki=ko; ko=tk; unsigned* tp=pi; pi=po; po=tp;
    }
    k_rank_build<<<nbN,256,0,stream>>>(pi, rank, minrank, N);
  }

  // ---- MIS rounds, gated by previous round's unmasked count ----
  for (int r=0; r<ROUNDS; ++r){
    const int* gate = counters + (r==0 ? 7 : (8+r-1));
    int* cnt = counters + 8 + r;
    k_mis_edge_min<<<egrid,256,0,stream>>>(row,col,minrank,mn,E,N,gate);
    k_mis_node_update<<<nbN,256,0,stream>>>(rank,minrank,mn,mis,mask,maskA,N,gate);
    k_mis_edge_prop<<<egrid,256,0,stream>>>(row,col,maskA,nbv,E,gate);
    k_mis_node_fin<<<nbN,256,0,stream>>>(rank,minrank,mask,maskA,nbv,N,cnt,gate);
  }

  // ---- clustering ----
  k_cl_init<<<nbN,256,0,stream>>>(rank,mis,minrank,mn,N);
  k_cl_edge<<<egrid,256,0,stream>>>(row,col,minrank,mn,E,N);
  k_cl_fin<<<nbN,256,0,stream>>>(minrank,mn,N);
  k_copy_u32<<<nbN,256,0,stream>>>(mis,cidx,N);
  k_scan_partials<<<Bn,256,0,stream>>>(cidx,bsums,N);
  k_scan_single<<<1,1024,0,stream>>>(bsums,Bn,(unsigned*)(counters+1));   // M
  k_scan_final<<<Bn,256,0,stream>>>(cidx,cidx,bsums,N);
  k_cl_map<<<nbN,256,0,stream>>>(rank,mis,cidx,map,counters+4,N);
  k_cl_cluster<<<nbN,256,0,stream>>>(mn,map,counters+4,cluster,N);
  k_gather_x<<<(N*(D/4)+255)/256,256,0,stream>>>((const float4*)x,(float4*)out,mis,cidx,N,D/4);

  // ---- coarsened edges: sort pairs, group, sum, filter self-loops ----
  k_pair_key<<<nbE,256,0,stream>>>(row,col,cluster,keyA,payA,E);
  {
    unsigned long long *ki=keyA,*ko=keyB; unsigned *pi=payA,*po=payB;
    for (int pass=0; pass<5; ++pass){   // 5x8 = 40 bits >= 34-bit keys
      int shift = pass*8;
      k_radix_hist<unsigned long long><<<Be,256,0,stream>>>(ki,E,shift,ghist,Be);
      k_scan_single<<<1,1024,0,stream>>>(ghist,256*Be,nullptr);
      k_radix_scatter<unsigned long long><<<Be,256,0,stream>>>(ki,pi,ko,po,E,shift,ghist,Be);
      unsigned long long* tk=ki; ki=ko; ko=tk; unsigned* tp=pi; pi=po; po=tp;
    }
    k_head_flags<<<nbE,256,0,stream>>>(ki,scanA,E);
    k_scan_partials<<<Be,256,0,stream>>>(scanA,bsums,E);
    k_scan_single<<<1,1024,0,stream>>>(bsums,Be,(unsigned*)(counters+2)); // U (unused)
    k_scan_final<<<Be,256,0,stream>>>(scanA,scanA,bsums,E);
    k_acc_vals<<<nbE,256,0,stream>>>(ki,pi,scanA,attr,vals,E);
    k_keep_flags<<<nbE,256,0,stream>>>(ki,scanB,E);
    k_scan_partials<<<Be,256,0,stream>>>(scanB,bsums,E);
    k_scan_single<<<1,1024,0,stream>>>(bsums,Be,(unsigned*)(counters+3)); // E'
    k_scan_final<<<Be,256,0,stream>>>(scanB,scanB,bsums,E);
    k_write_edges<<<nbE,256,0,stream>>>(ki,scanA,scanB,vals,out,counters,E,D);
  }
  k_write_nodes<<<nbN,256,0,stream>>>(cluster,mis,score,out,counters,N,D);
}

// Round 2
// 1226.144 us; speedup vs baseline: 2.3520x; 2.3520x over previous
//
#include <hip/hip_runtime.h>
#include <stdint.h>

#define RT 256
#define RTILE 4096
#define ROUNDS 16

// ============================ init ============================
__global__ void k_init_counters(int* counters){
  int t = threadIdx.x;
  counters[t] = 0;
  if (t == 7) counters[7] = 1;  // sentinel gate for round 0
}
__global__ void k_init_nodes(int* mask, int* mis, int* nb, int* mn, int N){
  int v = blockIdx.x*blockDim.x + threadIdx.x;
  if (v < N){ mask[v]=0; mis[v]=0; nb[v]=0; mn[v]=N; }
}
__global__ void k_zero_vals(float* vals, int E){
  int i = blockIdx.x*blockDim.x + threadIdx.x;
  if (i < E) vals[i]=0.f;
}

// ============================ rank (stable argsort of score) ============================
__global__ void k_score_key(const float* score, unsigned* keys, unsigned* pay, int N){
  int i = blockIdx.x*blockDim.x+threadIdx.x;
  if (i<N){
    unsigned b = __float_as_uint(score[i]);
    b ^= ((int)b < 0) ? 0xFFFFFFFFu : 0x80000000u;   // order-preserving float->uint
    keys[i]=b; pay[i]=(unsigned)i;
  }
}
__global__ void k_rank_build(const unsigned* pay, int* rank, int* minrank, int N){
  int p = blockIdx.x*blockDim.x+threadIdx.x;
  if (p<N){ int v = (int)pay[p]; rank[v]=p; minrank[v]=p; }
}

// ============================ radix sort (stable LSD, 8-bit digits) ============================
template<typename K>
__global__ void k_radix_hist(const K* __restrict__ keys, int n, int shift,
                             unsigned* __restrict__ ghist, int numBlocks){
  __shared__ unsigned h[256];
  int t=threadIdx.x, b=blockIdx.x;
  h[t]=0; __syncthreads();
  int base = b*RTILE;
  for (int j=t; j<RTILE; j+=RT){
    int i = base+j;
    if (i<n){
      unsigned d = (unsigned)((keys[i]>>shift)&(K)255);
      atomicAdd(&h[d],1u);
    }
  }
  __syncthreads();
  ghist[(size_t)t*numBlocks + b] = h[t];
}

template<typename K>
__global__ void k_radix_scatter(const K* __restrict__ keysIn, const unsigned* __restrict__ payIn,
                                K* __restrict__ keysOut, unsigned* __restrict__ payOut,
                                int n, int shift, const unsigned* __restrict__ gbase, int numBlocks){
  __shared__ unsigned carry[256];
  int t=threadIdx.x, b=blockIdx.x;
  carry[t]=0; __syncthreads();
  int lane = t&63, wave = t>>6;
  int base = b*RTILE;
  for (int r=0; r<RTILE/RT; ++r){
    int i = base + r*RT + t;
    bool valid = i<n;
    K k = valid ? keysIn[i] : (K)0;
    unsigned pay = valid ? payIn[i] : 0u;
    unsigned d = (unsigned)((k>>shift)&(K)255);
    unsigned off=0;
    // serialize 4 waves in order for a stable within-block rank
    for (int w=0; w<RT/64; ++w){
      if (wave==w){
        unsigned long long m = __ballot(valid);
        #pragma unroll
        for (int bit=0; bit<8; ++bit){
          unsigned long long bb = __ballot((d>>bit)&1u);
          m &= ((d>>bit)&1u) ? bb : ~bb;
        }
        int lr = __popcll(m & ((1ull<<lane)-1ull));
        unsigned cb = carry[d];
        off = cb + (unsigned)lr;
        if (valid && lr==0) carry[d] = cb + (unsigned)__popcll(m);  // unique leader per digit
      }
      __syncthreads();
    }
    if (valid){
      unsigned pos = gbase[(size_t)d*numBlocks + b] + off;
      keysOut[pos]=k; payOut[pos]=pay;
    }
  }
}

// single-block exclusive scan (in-place), ONLY for small arrays (n <= 4096)
__global__ void k_scan_single(unsigned* data, int n, unsigned* total){
  __shared__ unsigned sh[1024];
  __shared__ unsigned carry;
  int t=threadIdx.x;
  if (t==0) carry=0;
  __syncthreads();
  for (int base=0; base<n; base+=4096){
    unsigned v[4]; unsigned s=0;
    int i0 = base + t*4;
    #pragma unroll
    for (int j=0;j<4;j++){ int i=i0+j; v[j] = (i<n)?data[i]:0u; s+=v[j]; }
    sh[t]=s; __syncthreads();
    for (int off=1; off<1024; off<<=1){
      unsigned x = (t>=off)? sh[t-off]:0u; __syncthreads();
      sh[t]+=x; __syncthreads();
    }
    unsigned excl = (t?sh[t-1]:0u) + carry;
    #pragma unroll
    for (int j=0;j<4;j++){ int i=i0+j; if(i<n){ unsigned o=v[j]; data[i]=excl; excl+=o; } }
    unsigned tot = sh[1023];
    __syncthreads();
    if (t==0) carry += tot;
    __syncthreads();
  }
  if (total && t==0) *total = carry;
}

// 3-kernel big exclusive scan
__global__ void k_scan_partials(const unsigned* __restrict__ in, unsigned* __restrict__ bsums, int n){
  __shared__ unsigned sh[256];
  int b=blockIdx.x, t=threadIdx.x;
  long base = (long)b*RTILE + (long)t*16;
  unsigned s=0;
  #pragma unroll
  for (int j=0;j<16;j++){ long i=base+j; if(i<n) s+=in[i]; }
  sh[t]=s; __syncthreads();
  for (int off=128; off>0; off>>=1){ if(t<off) sh[t]+=sh[t+off]; __syncthreads(); }
  if (t==0) bsums[b]=sh[0];
}
__global__ void k_scan_final(const unsigned* __restrict__ in, unsigned* __restrict__ out,
                             const unsigned* __restrict__ bsums, int n){
  __shared__ unsigned sh[256];
  int b=blockIdx.x, t=threadIdx.x;
  long base = (long)b*RTILE + (long)t*16;
  unsigned v[16]; unsigned s=0;
  #pragma unroll
  for (int j=0;j<16;j++){ long i=base+j; v[j]=(i<n)?in[i]:0u; s+=v[j]; }
  sh[t]=s; __syncthreads();
  for (int off=1; off<256; off<<=1){
    unsigned x=(t>=off)?sh[t-off]:0u; __syncthreads(); sh[t]+=x; __syncthreads();
  }
  unsigned run=(t?sh[t-1]:0u)+bsums[b];
  #pragma unroll
  for (int j=0;j<16;j++){ long i=base+j; if(i<n){ unsigned o=v[j]; out[i]=run; run+=o; } }
}

// ============================ MIS rounds (gated; replicate reference exactly) ============================
__global__ void k_mis_edge_min(const int* __restrict__ row, const int* __restrict__ col,
                               const int* __restrict__ minrank, int* __restrict__ mn,
                               int E, int N, const int* gate){
  if (*gate == 0) return;
  for (int e = blockIdx.x*blockDim.x+threadIdx.x; e < E; e += gridDim.x*blockDim.x){
    int v = minrank[row[e]];
    if (v < N) atomicMin(&mn[col[e]], v);
  }
}
__global__ void k_mis_node_update(const int* __restrict__ rank, int* __restrict__ minrank,
                                  int* __restrict__ mn, int* __restrict__ mis,
                                  const int* __restrict__ mask, int* __restrict__ maskA,
                                  int N, const int* gate){
  if (*gate==0) return;
  int v = blockIdx.x*blockDim.x+threadIdx.x;
  if (v<N){
    int mr = min(minrank[v], mn[v]);
    minrank[v]=mr;
    mn[v]=N;                       // re-init for next round
    int nm = (rank[v]==mr) & (mask[v]==0);
    if (nm) mis[v]=1;
    maskA[v] = mask[v] | nm;       // mask |= mis
  }
}
__global__ void k_mis_edge_prop(const int* __restrict__ row, const int* __restrict__ col,
                                const int* __restrict__ maskA, int* __restrict__ nb,
                                int E, const int* gate){
  if (*gate==0) return;
  for (int e = blockIdx.x*blockDim.x+threadIdx.x; e < E; e += gridDim.x*blockDim.x){
    if (maskA[row[e]]) nb[col[e]]=1;
  }
}
__global__ void k_mis_node_fin(const int* __restrict__ rank, int* __restrict__ minrank,
                               int* __restrict__ mask, const int* __restrict__ maskA,
                               int* __restrict__ nb, int N, int* cnt, const int* gate){
  if (*gate==0) return;
  int v = blockIdx.x*blockDim.x+threadIdx.x;
  int um = 0;
  if (v<N){
    int mk = maskA[v] | nb[v];
    mask[v]=mk; nb[v]=0;
    minrank[v] = mk ? N : rank[v];
    um = (mk==0);
  }
  unsigned long long bm = __ballot(um);
  if ((threadIdx.x&63)==0 && bm) atomicAdd(cnt, (int)__popcll(bm));
}

// ============================ clustering ============================
__global__ void k_cl_init(const int* rank, const int* mis, int* minrank, int* mn, int N){
  int v = blockIdx.x*blockDim.x+threadIdx.x;
  if (v<N){ minrank[v] = mis[v]? rank[v] : N; mn[v]=N; }
}
__global__ void k_cl_edge(const int* __restrict__ row, const int* __restrict__ col,
                          const int* __restrict__ minrank, int* __restrict__ mn, int E, int N){
  for (int e = blockIdx.x*blockDim.x+threadIdx.x; e < E; e += gridDim.x*blockDim.x){
    int x = minrank[row[e]];
    if (x < N) atomicMin(&mn[col[e]], x);
  }
}
__global__ void k_cl_fin(const int* minrank, int* mn, int N){
  int v = blockIdx.x*blockDim.x+threadIdx.x;
  if (v<N) mn[v] = min(mn[v], minrank[v]);
}
__global__ void k_copy_u32(const int* in, unsigned* out, int N){
  int v = blockIdx.x*blockDim.x+threadIdx.x;
  if (v<N) out[v]=(unsigned)in[v];
}
__global__ void k_cl_map(const int* rank, const int* mis, const unsigned* cidx,
                         int* map, int* rmax, int N){
  int v = blockIdx.x*blockDim.x+threadIdx.x;
  if (v<N && mis[v]){ map[rank[v]] = (int)cidx[v]; atomicMax(rmax, rank[v]); }
}
__global__ void k_cl_cluster(const int* mn, const int* map, const int* rmax, int* cluster, int N){
  int v = blockIdx.x*blockDim.x+threadIdx.x;
  if (v<N){
    int mr = mn[v];
    if (mr >= N) mr = *rmax;      // JAX OOB-gather clamp semantics for uncovered nodes
    cluster[v] = map[mr];
  }
}
__global__ void k_gather_x(const float4* __restrict__ x, float4* __restrict__ out,
                           const int* __restrict__ mis, const unsigned* __restrict__ cidx,
                           int N, int D4){
  int t = blockIdx.x*blockDim.x+threadIdx.x;
  int v = t / D4, q = t - v*D4;
  if (v<N && mis[v]) out[(size_t)cidx[v]*D4 + q] = x[(size_t)v*D4 + q];
}

// ============================ coarsened-edge aggregation ============================
// payload of the pair sort = attr bits (no index gather needed later)
__global__ void k_pair_key(const int* __restrict__ row, const int* __restrict__ col,
                           const int* __restrict__ cluster, const float* __restrict__ attr,
                           unsigned long long* __restrict__ keys, unsigned* __restrict__ pay, int E){
  int e = blockIdx.x*blockDim.x+threadIdx.x;
  if (e<E){
    unsigned a = (unsigned)cluster[row[e]], b=(unsigned)cluster[col[e]];
    keys[e] = ((unsigned long long)a<<17) | b;   // M <= N=100000 < 2^17
    pay[e]=__float_as_uint(attr[e]);
  }
}
// fused head + keep flags (one pass over keys)
__global__ void k_flags(const unsigned long long* __restrict__ keys,
                        unsigned* __restrict__ fhead, unsigned* __restrict__ fkeep, int E){
  int i = blockIdx.x*blockDim.x+threadIdx.x;
  if (i<E){
    unsigned long long k = keys[i];
    unsigned head = (i==0) || (k != keys[i-1]);
    unsigned a=(unsigned)(k>>17), b=(unsigned)(k&0x1FFFFull);
    fhead[i]=head;
    fkeep[i]=(head && a!=b) ? 1u : 0u;
  }
}
// wave-segmented sum of sorted (key, attr) pairs; one atomic per segment-per-wave
__global__ void k_acc_seg(const unsigned long long* __restrict__ keys,
                          const unsigned* __restrict__ pay,
                          const unsigned* __restrict__ excl1,
                          float* __restrict__ vals, int E){
  int i = blockIdx.x*blockDim.x+threadIdx.x;
  int lane = threadIdx.x & 63;
  bool valid = i < E;
  unsigned long long k = valid ? keys[i] : ~0ull;
  float v = valid ? __uint_as_float(pay[i]) : 0.f;
  #pragma unroll
  for (int off=1; off<64; off<<=1){
    float o = __shfl_up(v, off);
    unsigned long long ko = __shfl_up(k, off);
    if (lane >= off && ko == k) v += o;   // sorted => equal keys contiguous
  }
  if (valid){
    unsigned long long knext = (i+1<E) ? keys[i+1] : ~0ull;
    if (lane==63 || k != knext){          // tail of segment (or wave-partial)
      unsigned head = (i==0) || (keys[i-1] != k);
      atomicAdd(&vals[excl1[i] + head - 1u], v);
    }
  }
}
__global__ void k_write_edges(const unsigned long long* __restrict__ keys,
                              const unsigned* __restrict__ excl1, const unsigned* __restrict__ excl2,
                              const float* __restrict__ vals, float* __restrict__ out,
                              const int* __restrict__ counters, int E, int D){
  int i = blockIdx.x*blockDim.x+threadIdx.x;
  if (i<E){
    int head=(i==0)||(keys[i]!=keys[i-1]);
    unsigned a=(unsigned)(keys[i]>>17), b=(unsigned)(keys[i]&0x1FFFFull);
    if (head && a!=b){
      unsigned opos = excl2[i];
      int M = counters[1], Ep = counters[3];
      size_t off = (size_t)M*D;
      out[off + opos] = (float)a;
      out[off + (size_t)Ep + opos] = (float)b;
      out[off + 2*(size_t)Ep + opos] = vals[excl1[i]];  // head => group = excl1[i]
    }
  }
}
__global__ void k_write_nodes(const int* __restrict__ cluster, const int* __restrict__ mis,
                              const float* __restrict__ score, float* __restrict__ out,
                              const int* __restrict__ counters, int N, int D){
  int v = blockIdx.x*blockDim.x+threadIdx.x;
  if (v<N){
    int M=counters[1], Ep=counters[3];
    size_t off = (size_t)M*D + 3*(size_t)Ep;
    out[off + v] = (float)cluster[v];
    out[off + (size_t)N + v] = mis[v] ? 1.f : 0.f;
    out[off + 2*(size_t)N + v] = score[v];
  }
}

// ============================ host ============================
extern "C" void kernel_launch(void* const* d_in, const int* in_sizes, int n_in,
                              void* d_out, int out_size, void* d_ws, size_t ws_size,
                              hipStream_t stream){
  const float* x     = (const float*)d_in[0];
  const int*   ei    = (const int*)d_in[1];
  const float* attr  = (const float*)d_in[2];
  const float* score = (const float*)d_in[3];
  int N = in_sizes[3];
  int E = in_sizes[2];
  int D = in_sizes[0]/N;
  const int* row = ei;
  const int* col = ei + E;
  float* out = (float*)d_out;

  char* p = (char*)d_ws;
  auto alloc = [&](size_t bytes)->char*{ char* r=p; p += ((bytes+255)/256)*256; return r; };
  unsigned long long* keyA = (unsigned long long*)alloc((size_t)E*8);
  unsigned long long* keyB = (unsigned long long*)alloc((size_t)E*8);
  unsigned* payA  = (unsigned*)alloc((size_t)E*4);
  unsigned* payB  = (unsigned*)alloc((size_t)E*4);
  unsigned* scanA = (unsigned*)alloc((size_t)E*4);
  unsigned* scanB = (unsigned*)alloc((size_t)E*4);
  float*    vals  = (float*)alloc((size_t)E*4);
  int* rank   = (int*)alloc((size_t)N*4);
  int* minrank= (int*)alloc((size_t)N*4);
  int* mn     = (int*)alloc((size_t)N*4);
  int* mis    = (int*)alloc((size_t)N*4);
  int* mask   = (int*)alloc((size_t)N*4);
  int* maskA  = (int*)alloc((size_t)N*4);
  int* nbv    = (int*)alloc((size_t)N*4);
  int* map    = (int*)alloc((size_t)N*4);
  unsigned* cidx = (unsigned*)alloc((size_t)N*4);
  int* cluster= (int*)alloc((size_t)N*4);
  int* counters=(int*)alloc(256*4);
  int Be = (E + RTILE-1)/RTILE;
  int Bn = (N + RTILE-1)/RTILE;
  unsigned* ghist = (unsigned*)alloc((size_t)256*Be*4);
  unsigned* bsums = (unsigned*)alloc(4096*4);

  int nbN = (N+255)/256, nbE = (E+255)/256;
  int egrid = 784;  // grid-stride edge kernels (cheap when gated off)

  // parallel exclusive scan, in-place; total (optional) -> device int
  auto big_scan = [&](unsigned* data, int n, unsigned* total){
    int B = (n + RTILE-1)/RTILE;
    k_scan_partials<<<B,256,0,stream>>>(data,bsums,n);
    k_scan_single<<<1,1024,0,stream>>>(bsums,B,total);
    k_scan_final<<<B,256,0,stream>>>(data,data,bsums,n);
  };

  k_init_counters<<<1,256,0,stream>>>(counters);
  k_init_nodes<<<nbN,256,0,stream>>>(mask,mis,nbv,mn,N);
  k_zero_vals<<<nbE,256,0,stream>>>(vals,E);

  // ---- rank = stable argsort(argsort(score)) via 4-pass LSD radix ----
  unsigned* ski = (unsigned*)keyA;
  unsigned* sko = (unsigned*)keyB;
  k_score_key<<<nbN,256,0,stream>>>(score, ski, payA, N);
  {
    unsigned *ki=ski,*ko=sko,*pi=payA,*po=payB;
    for (int pass=0; pass<4; ++pass){
      int shift = pass*8;
      k_radix_hist<unsigned><<<Bn,256,0,stream>>>(ki,N,shift,ghist,Bn);
      big_scan(ghist,256*Bn,nullptr);
      k_radix_scatter<unsigned><<<Bn,256,0,stream>>>(ki,pi,ko,po,N,shift,ghist,Bn);
      unsigned* tk=ki; ki=ko; ko=tk; unsigned* tp=pi; pi=po; po=tp;
    }
    k_rank_build<<<nbN,256,0,stream>>>(pi, rank, minrank, N);
  }

  // ---- MIS rounds, gated by previous round's unmasked count ----
  for (int r=0; r<ROUNDS; ++r){
    const int* gate = counters + (r==0 ? 7 : (8+r-1));
    int* cnt = counters + 8 + r;
    k_mis_edge_min<<<egrid,256,0,stream>>>(row,col,minrank,mn,E,N,gate);
    k_mis_node_update<<<nbN,256,0,stream>>>(rank,minrank,mn,mis,mask,maskA,N,gate);
    k_mis_edge_prop<<<egrid,256,0,stream>>>(row,col,maskA,nbv,E,gate);
    k_mis_node_fin<<<nbN,256,0,stream>>>(rank,minrank,mask,maskA,nbv,N,cnt,gate);
  }

  // ---- clustering ----
  k_cl_init<<<nbN,256,0,stream>>>(rank,mis,minrank,mn,N);
  k_cl_edge<<<egrid,256,0,stream>>>(row,col,minrank,mn,E,N);
  k_cl_fin<<<nbN,256,0,stream>>>(minrank,mn,N);
  k_copy_u32<<<nbN,256,0,stream>>>(mis,cidx,N);
  k_scan_partials<<<Bn,256,0,stream>>>(cidx,bsums,N);
  k_scan_single<<<1,1024,0,stream>>>(bsums,Bn,(unsigned*)(counters+1));   // M
  k_scan_final<<<Bn,256,0,stream>>>(cidx,cidx,bsums,N);
  k_cl_map<<<nbN,256,0,stream>>>(rank,mis,cidx,map,counters+4,N);
  k_cl_cluster<<<nbN,256,0,stream>>>(mn,map,counters+4,cluster,N);
  k_gather_x<<<(N*(D/4)+255)/256,256,0,stream>>>((const float4*)x,(float4*)out,mis,cidx,N,D/4);

  // ---- coarsened edges: sort (pair,attr), group, segment-sum, filter self-loops ----
  k_pair_key<<<nbE,256,0,stream>>>(row,col,cluster,attr,keyA,payA,E);
  {
    unsigned long long *ki=keyA,*ko=keyB; unsigned *pi=payA,*po=payB;
    for (int pass=0; pass<5; ++pass){   // 5x8 = 40 bits >= 34-bit keys
      int shift = pass*8;
      k_radix_hist<unsigned long long><<<Be,256,0,stream>>>(ki,E,shift,ghist,Be);
      big_scan(ghist,256*Be,nullptr);
      k_radix_scatter<unsigned long long><<<Be,256,0,stream>>>(ki,pi,ko,po,E,shift,ghist,Be);
      unsigned long long* tk=ki; ki=ko; ko=tk; unsigned* tp=pi; pi=po; po=tp;
    }
    k_flags<<<nbE,256,0,stream>>>(ki,scanA,scanB,E);
    big_scan(scanA,E,(unsigned*)(counters+2));                      // group ids
    big_scan(scanB,E,(unsigned*)(counters+3));                      // E'
    k_acc_seg<<<nbE,256,0,stream>>>(ki,pi,scanA,vals,E);
    k_write_edges<<<nbE,256,0,stream>>>(ki,scanA,scanB,vals,out,counters,E,D);
  }
  k_write_nodes<<<nbN,256,0,stream>>>(cluster,mis,score,out,counters,N,D);
}

// Round 3
// 1094.106 us; speedup vs baseline: 2.6358x; 1.1207x over previous
//
#include <hip/hip_runtime.h>
#include <stdint.h>

#define RTILE 4096
#define ROUNDS 12

// counters layout: [1]=M, [2]=group total, [3]=E', [4]=rmax, [5..6] unused,
// [7]=constant 1 (always-on gate), [8..8+ROUNDS-1]=per-round unmasked count,
// [32..35]=radix pass gates for pair sort, [36]=sh (cluster-id bit width)

// ============================ init ============================
__global__ void k_init_counters(int* counters){
  int t = threadIdx.x;
  counters[t] = 0;
  if (t == 7) counters[7] = 1;
}
__global__ void k_init_nodes(int* mis, int N){
  int v = blockIdx.x*blockDim.x + threadIdx.x;
  if (v < N) mis[v]=0;
}
__global__ void k_zero_vals(float* vals, int E){
  int i = blockIdx.x*blockDim.x + threadIdx.x;
  if (i < E) vals[i]=0.f;
}

// ============================ key-making ============================
__global__ void k_score_key(const float* score, unsigned* keys, unsigned* pay, int N){
  int i = blockIdx.x*blockDim.x+threadIdx.x;
  if (i<N){
    unsigned b = __float_as_uint(score[i]);
    b ^= ((int)b < 0) ? 0xFFFFFFFFu : 0x80000000u;
    keys[i]=b; pay[i]=(unsigned)i;
  }
}
__global__ void k_rank_build(const unsigned* pay, int* rank, int* pm, int N){
  int p = blockIdx.x*blockDim.x+threadIdx.x;
  if (p<N){ int v = (int)pay[p]; rank[v]=p; pm[v]=p; }
}
__global__ void k_make_colrow(const int* __restrict__ row, const int* __restrict__ col,
                              unsigned* __restrict__ keys, unsigned* __restrict__ pay, int E){
  int e = blockIdx.x*blockDim.x+threadIdx.x;
  if (e<E){ keys[e]=(unsigned)col[e]; pay[e]=(unsigned)row[e]; }
}

// ============================ radix sort (stable LSD, 9-bit digits) ============================
template<typename K, int TILE>
__global__ void k_radix_hist(const K* __restrict__ keys, int n, int shift,
                             unsigned* __restrict__ ghist, int numBlocks, const int* gate){
  if (*gate==0) return;
  __shared__ unsigned h[512];
  int t=threadIdx.x, b=blockIdx.x;
  h[t]=0; h[t+256]=0; __syncthreads();
  int base = b*TILE;
  for (int j=t; j<TILE; j+=256){
    int i = base+j;
    if (i<n){
      unsigned d = (unsigned)((keys[i]>>shift)&(K)511);
      atomicAdd(&h[d],1u);
    }
  }
  __syncthreads();
  ghist[(size_t)t*numBlocks + b] = h[t];
  ghist[(size_t)(t+256)*numBlocks + b] = h[t+256];
}

template<typename K, int TILE>
__global__ void k_radix_scatter(const K* __restrict__ keysIn, const unsigned* __restrict__ payIn,
                                K* __restrict__ keysOut, unsigned* __restrict__ payOut,
                                int n, int shift, const unsigned* __restrict__ gbase,
                                int numBlocks, const int* gate){
  int t=threadIdx.x, b=blockIdx.x;
  int base = b*TILE;
  if (*gate==0){  // identity copy keeps ping-pong parity
    for (int j=t; j<TILE; j+=256){
      int i = base+j;
      if (i<n){ keysOut[i]=keysIn[i]; payOut[i]=payIn[i]; }
    }
    return;
  }
  __shared__ unsigned carry[512];
  carry[t]=0; carry[t+256]=0; __syncthreads();
  int lane = t&63, wave = t>>6;
  for (int r=0; r<TILE/256; ++r){
    int i = base + r*256 + t;
    bool valid = i<n;
    K k = valid ? keysIn[i] : (K)0;
    unsigned pay = valid ? payIn[i] : 0u;
    unsigned d = (unsigned)((k>>shift)&(K)511);
    unsigned off=0;
    for (int w=0; w<4; ++w){
      if (wave==w){
        unsigned long long m = __ballot(valid);
        #pragma unroll
        for (int bit=0; bit<9; ++bit){
          unsigned long long bb = __ballot((d>>bit)&1u);
          m &= ((d>>bit)&1u) ? bb : ~bb;
        }
        int lr = __popcll(m & ((1ull<<lane)-1ull));
        unsigned cb = carry[d];
        off = cb + (unsigned)lr;
        if (valid && lr==0) carry[d] = cb + (unsigned)__popcll(m);
      }
      __syncthreads();
    }
    if (valid){
      unsigned pos = gbase[(size_t)d*numBlocks + b] + off;
      keysOut[pos]=k; payOut[pos]=pay;
    }
  }
}

// single-block exclusive scan (in-place)
__global__ void k_scan_single(unsigned* data, int n, unsigned* total, const int* gate){
  if (*gate==0) return;
  __shared__ unsigned sh[1024];
  __shared__ unsigned carry;
  int t=threadIdx.x;
  if (t==0) carry=0;
  __syncthreads();
  for (int base=0; base<n; base+=4096){
    unsigned v[4]; unsigned s=0;
    int i0 = base + t*4;
    #pragma unroll
    for (int j=0;j<4;j++){ int i=i0+j; v[j] = (i<n)?data[i]:0u; s+=v[j]; }
    sh[t]=s; __syncthreads();
    for (int off=1; off<1024; off<<=1){
      unsigned x = (t>=off)? sh[t-off]:0u; __syncthreads();
      sh[t]+=x; __syncthreads();
    }
    unsigned excl = (t?sh[t-1]:0u) + carry;
    #pragma unroll
    for (int j=0;j<4;j++){ int i=i0+j; if(i<n){ unsigned o=v[j]; data[i]=excl; excl+=o; } }
    unsigned tot = sh[1023];
    __syncthreads();
    if (t==0) carry += tot;
    __syncthreads();
  }
  if (total && t==0) *total = carry;
}

// 3-kernel big exclusive scan
__global__ void k_scan_partials(const unsigned* __restrict__ in, unsigned* __restrict__ bsums,
                                int n, const int* gate){
  if (*gate==0) return;
  __shared__ unsigned sh[256];
  int b=blockIdx.x, t=threadIdx.x;
  long base = (long)b*RTILE + (long)t*16;
  unsigned s=0;
  #pragma unroll
  for (int j=0;j<16;j++){ long i=base+j; if(i<n) s+=in[i]; }
  sh[t]=s; __syncthreads();
  for (int off=128; off>0; off>>=1){ if(t<off) sh[t]+=sh[t+off]; __syncthreads(); }
  if (t==0) bsums[b]=sh[0];
}
__global__ void k_scan_final(const unsigned* __restrict__ in, unsigned* __restrict__ out,
                             const unsigned* __restrict__ bsums, int n, const int* gate){
  if (*gate==0) return;
  __shared__ unsigned sh[256];
  int b=blockIdx.x, t=threadIdx.x;
  long base = (long)b*RTILE + (long)t*16;
  unsigned v[16]; unsigned s=0;
  #pragma unroll
  for (int j=0;j<16;j++){ long i=base+j; v[j]=(i<n)?in[i]:0u; s+=v[j]; }
  sh[t]=s; __syncthreads();
  for (int off=1; off<256; off<<=1){
    unsigned x=(t>=off)?sh[t-off]:0u; __syncthreads(); sh[t]+=x; __syncthreads();
  }
  unsigned run=(t?sh[t-1]:0u)+bsums[b];
  #pragma unroll
  for (int j=0;j<16;j++){ long i=base+j; if(i<n){ unsigned o=v[j]; out[i]=run; run+=o; } }
}

// ============================ CSR offsets from sorted cols ============================
__global__ void k_build_off(const unsigned* __restrict__ scol, int* __restrict__ off, int E, int N){
  int i = blockIdx.x*blockDim.x+threadIdx.x;
  if (i>=E) return;
  int c = (int)scol[i];
  int p = (i==0) ? -1 : (int)scol[i-1];
  for (int v=p+1; v<=c; ++v) off[v]=i;
  if (i==E-1){ for (int v=c+1; v<=N; ++v) off[v]=E; }
}

// ============================ MIS rounds (gather form; pm[v]=mask?N:rank) ============================
__global__ void k_round1(const int* __restrict__ off, const int* __restrict__ nbr,
                         const int* __restrict__ pm, int* __restrict__ mis,
                         int* __restrict__ maskA, int N, const int* gate){
  if (*gate==0) return;
  int v = blockIdx.x*blockDim.x+threadIdx.x;
  if (v>=N) return;
  int p = pm[v];
  if (p == N){ maskA[v]=1; return; }       // masked node can never newly join MIS
  int m = p;
  int s=off[v], e=off[v+1];
  for (int j=s; j<e; ++j){ int u=nbr[j]; m = min(m, pm[u]); }
  int nm = (m == p);                        // p == rank[v] when unmasked; ranks unique
  if (nm) mis[v]=1;
  maskA[v] = nm;
}
__global__ void k_round2(const int* __restrict__ off, const int* __restrict__ nbr,
                         const int* __restrict__ maskA, int* __restrict__ pm,
                         int N, int* cnt, const int* gate){
  if (*gate==0) return;
  int v = blockIdx.x*blockDim.x+threadIdx.x;
  int um = 0;
  if (v<N){
    int mk = maskA[v];
    int s=off[v], e=off[v+1];
    for (int j=s; j<e && !mk; ++j) mk |= maskA[nbr[j]];
    if (mk) pm[v] = N;                      // else pm stays == rank[v]
    um = !mk;
  }
  unsigned long long bm = __ballot(um);
  if ((threadIdx.x&63)==0 && bm) atomicAdd(cnt, (int)__popcll(bm));
}

// ============================ clustering ============================
__global__ void k_cl_init(const int* rank, const int* mis, int* pm, int N){
  int v = blockIdx.x*blockDim.x+threadIdx.x;
  if (v<N) pm[v] = mis[v] ? rank[v] : N;
}
__global__ void k_cl_gather(const int* __restrict__ off, const int* __restrict__ nbr,
                            const int* __restrict__ pm, int* __restrict__ mn, int N){
  int v = blockIdx.x*blockDim.x+threadIdx.x;
  if (v>=N) return;
  int m = pm[v];
  int s=off[v], e=off[v+1];
  for (int j=s; j<e; ++j) m = min(m, pm[nbr[j]]);
  mn[v] = m;
}
__global__ void k_copy_u32(const int* in, unsigned* out, int N){
  int v = blockIdx.x*blockDim.x+threadIdx.x;
  if (v<N) out[v]=(unsigned)in[v];
}
__global__ void k_cl_map(const int* rank, const int* mis, const unsigned* cidx,
                         int* map, int* rmax, int N){
  int v = blockIdx.x*blockDim.x+threadIdx.x;
  if (v<N && mis[v]){ map[rank[v]] = (int)cidx[v]; atomicMax(rmax, rank[v]); }
}
__global__ void k_cl_cluster(const int* mn, const int* map, const int* rmax, int* cluster, int N){
  int v = blockIdx.x*blockDim.x+threadIdx.x;
  if (v<N){
    int mr = mn[v];
    if (mr >= N) mr = *rmax;                // JAX OOB-gather clamp semantics
    cluster[v] = map[mr];
  }
}
__global__ void k_gather_x(const float4* __restrict__ x, float4* __restrict__ out,
                           const int* __restrict__ mis, const unsigned* __restrict__ cidx,
                           int N, int D4){
  int t = blockIdx.x*blockDim.x+threadIdx.x;
  int v = t / D4, q = t - v*D4;
  if (v<N && mis[v]) out[(size_t)cidx[v]*D4 + q] = x[(size_t)v*D4 + q];
}

// ============================ coarsened-edge aggregation ============================
__global__ void k_set_gates(int* counters){
  int M = counters[1];
  int sh = (M<=1) ? 1 : (32-__clz((unsigned)(M-1)));
  int kb = 2*sh;                            // max key bits
  counters[36] = sh;
  counters[32] = 1;
  counters[33] = (9  < kb);
  counters[34] = (18 < kb);
  counters[35] = (27 < kb);
}
__global__ void k_pair_key(const int* __restrict__ row, const int* __restrict__ col,
                           const int* __restrict__ cluster, const float* __restrict__ attr,
                           unsigned long long* __restrict__ keys, unsigned* __restrict__ pay,
                           const int* __restrict__ counters, int E){
  int e = blockIdx.x*blockDim.x+threadIdx.x;
  if (e<E){
    int sh = counters[36];
    unsigned a = (unsigned)cluster[row[e]], b=(unsigned)cluster[col[e]];
    keys[e] = ((unsigned long long)a<<sh) | b;
    pay[e] = __float_as_uint(attr[e]);
  }
}
__global__ void k_flags(const unsigned long long* __restrict__ keys,
                        unsigned* __restrict__ fhead, unsigned* __restrict__ fkeep,
                        const int* __restrict__ counters, int E){
  int i = blockIdx.x*blockDim.x+threadIdx.x;
  if (i<E){
    int sh = counters[36];
    unsigned long long k = keys[i];
    unsigned head = (i==0) || (k != keys[i-1]);
    unsigned a=(unsigned)(k>>sh), b=(unsigned)(k & ((1ull<<sh)-1ull));
    fhead[i]=head;
    fkeep[i]=(head && a!=b) ? 1u : 0u;
  }
}
__global__ void k_acc_seg(const unsigned long long* __restrict__ keys,
                          const unsigned* __restrict__ pay,
                          const unsigned* __restrict__ excl1,
                          float* __restrict__ vals, int E){
  int i = blockIdx.x*blockDim.x+threadIdx.x;
  int lane = threadIdx.x & 63;
  bool valid = i < E;
  unsigned long long k = valid ? keys[i] : ~0ull;
  float v = valid ? __uint_as_float(pay[i]) : 0.f;
  #pragma unroll
  for (int off=1; off<64; off<<=1){
    float o = __shfl_up(v, off);
    unsigned long long ko = __shfl_up(k, off);
    if (lane >= off && ko == k) v += o;
  }
  if (valid){
    unsigned long long knext = (i+1<E) ? keys[i+1] : ~0ull;
    if (lane==63 || k != knext){
      unsigned head = (i==0) || (keys[i-1] != k);
      atomicAdd(&vals[excl1[i] + head - 1u], v);
    }
  }
}
__global__ void k_write_edges(const unsigned long long* __restrict__ keys,
                              const unsigned* __restrict__ excl1, const unsigned* __restrict__ excl2,
                              const float* __restrict__ vals, float* __restrict__ out,
                              const int* __restrict__ counters, int E, int D){
  int i = blockIdx.x*blockDim.x+threadIdx.x;
  if (i<E){
    int sh = counters[36];
    int head=(i==0)||(keys[i]!=keys[i-1]);
    unsigned a=(unsigned)(keys[i]>>sh), b=(unsigned)(keys[i] & ((1ull<<sh)-1ull));
    if (head && a!=b){
      unsigned opos = excl2[i];
      int M = counters[1], Ep = counters[3];
      size_t off = (size_t)M*D;
      out[off + opos] = (float)a;
      out[off + (size_t)Ep + opos] = (float)b;
      out[off + 2*(size_t)Ep + opos] = vals[excl1[i]];
    }
  }
}
__global__ void k_write_nodes(const int* __restrict__ cluster, const int* __restrict__ mis,
                              const float* __restrict__ score, float* __restrict__ out,
                              const int* __restrict__ counters, int N, int D){
  int v = blockIdx.x*blockDim.x+threadIdx.x;
  if (v<N){
    int M=counters[1], Ep=counters[3];
    size_t off = (size_t)M*D + 3*(size_t)Ep;
    out[off + v] = (float)cluster[v];
    out[off + (size_t)N + v] = mis[v] ? 1.f : 0.f;
    out[off + 2*(size_t)N + v] = score[v];
  }
}

// ============================ host ============================
extern "C" void kernel_launch(void* const* d_in, const int* in_sizes, int n_in,
                              void* d_out, int out_size, void* d_ws, size_t ws_size,
                              hipStream_t stream){
  const float* x     = (const float*)d_in[0];
  const int*   ei    = (const int*)d_in[1];
  const float* attr  = (const float*)d_in[2];
  const float* score = (const float*)d_in[3];
  int N = in_sizes[3];
  int E = in_sizes[2];
  int D = in_sizes[0]/N;
  const int* row = ei;
  const int* col = ei + E;
  float* out = (float*)d_out;

  char* p = (char*)d_ws;
  auto alloc = [&](size_t bytes)->char*{ char* r=p; p += ((bytes+255)/256)*256; return r; };
  unsigned long long* keyA = (unsigned long long*)alloc((size_t)E*8);
  unsigned long long* keyB = (unsigned long long*)alloc((size_t)E*8);
  unsigned* payA  = (unsigned*)alloc((size_t)E*4);
  unsigned* payB  = (unsigned*)alloc((size_t)E*4);
  unsigned* scanA = (unsigned*)alloc((size_t)E*4);
  unsigned* scanB = (unsigned*)alloc((size_t)E*4);
  float*    vals  = (float*)alloc((size_t)E*4);
  int* csr_row = (int*)alloc((size_t)E*4);
  int* off     = (int*)alloc((size_t)(N+1)*4);
  int* rank   = (int*)alloc((size_t)N*4);
  int* pm     = (int*)alloc((size_t)N*4);
  int* mis    = (int*)alloc((size_t)N*4);
  int* maskA  = (int*)alloc((size_t)N*4);
  int* mnArr  = (int*)alloc((size_t)N*4);
  int* map    = (int*)alloc((size_t)N*4);
  unsigned* cidx = (unsigned*)alloc((size_t)N*4);
  int* cluster= (int*)alloc((size_t)N*4);
  int* counters=(int*)alloc(256*4);
  int Be = (E + RTILE-1)/RTILE;           // 4096-tiles over E
  int Bn1k = (N + 1023)/1024;             // 1024-tiles over N
  unsigned* ghist = (unsigned*)alloc((size_t)512*Be*4);
  unsigned* bsums = (unsigned*)alloc(4096*4);

  int nbN = (N+255)/256, nbE = (E+255)/256;
  const int* ON = counters+7;             // always-on gate

  auto big_scan = [&](unsigned* data, int n, unsigned* total, const int* gate){
    int B = (n + RTILE-1)/RTILE;
    k_scan_partials<<<B,256,0,stream>>>(data,bsums,n,gate);
    k_scan_single<<<1,1024,0,stream>>>(bsums,B,total,gate);
    k_scan_final<<<B,256,0,stream>>>(data,data,bsums,n,gate);
  };

  k_init_counters<<<1,256,0,stream>>>(counters);
  k_init_nodes<<<nbN,256,0,stream>>>(mis,N);
  k_zero_vals<<<nbE,256,0,stream>>>(vals,E);

  // ---- CSR build: sort (col -> row) by col, 2 passes of 9 bits ----
  k_make_colrow<<<nbE,256,0,stream>>>(row,col,(unsigned*)keyA,payA,E);
  k_radix_hist<unsigned,RTILE><<<Be,256,0,stream>>>((unsigned*)keyA,E,0,ghist,Be,ON);
  big_scan(ghist,512*Be,nullptr,ON);
  k_radix_scatter<unsigned,RTILE><<<Be,256,0,stream>>>((unsigned*)keyA,payA,(unsigned*)keyB,payB,E,0,ghist,Be,ON);
  k_radix_hist<unsigned,RTILE><<<Be,256,0,stream>>>((unsigned*)keyB,E,9,ghist,Be,ON);
  big_scan(ghist,512*Be,nullptr,ON);
  k_radix_scatter<unsigned,RTILE><<<Be,256,0,stream>>>((unsigned*)keyB,payB,scanA,(unsigned*)csr_row,E,9,ghist,Be,ON);
  k_build_off<<<nbE,256,0,stream>>>(scanA,off,E,N);

  // ---- rank = stable argsort(argsort(score)), 4 passes of 9 bits, TILE=1024 ----
  k_score_key<<<nbN,256,0,stream>>>(score,(unsigned*)keyA,payA,N);
  {
    unsigned *ki=(unsigned*)keyA,*ko=(unsigned*)keyB,*pi=payA,*po=payB;
    for (int pass=0; pass<4; ++pass){
      int shift = pass*9;
      k_radix_hist<unsigned,1024><<<Bn1k,256,0,stream>>>(ki,N,shift,ghist,Bn1k,ON);
      big_scan(ghist,512*Bn1k,nullptr,ON);
      k_radix_scatter<unsigned,1024><<<Bn1k,256,0,stream>>>(ki,pi,ko,po,N,shift,ghist,Bn1k,ON);
      unsigned* tk=ki; ki=ko; ko=tk; unsigned* tp=pi; pi=po; po=tp;
    }
    k_rank_build<<<nbN,256,0,stream>>>(pi, rank, pm, N);
  }

  // ---- MIS rounds: 2 gather kernels per round, gated on convergence ----
  for (int r=0; r<ROUNDS; ++r){
    const int* gate = (r==0) ? ON : (counters + 8 + r - 1);
    int* cnt = counters + 8 + r;
    k_round1<<<nbN,256,0,stream>>>(off,csr_row,pm,mis,maskA,N,gate);
    k_round2<<<nbN,256,0,stream>>>(off,csr_row,maskA,pm,N,cnt,gate);
  }

  // ---- clustering (gather form) ----
  k_cl_init<<<nbN,256,0,stream>>>(rank,mis,pm,N);
  k_cl_gather<<<nbN,256,0,stream>>>(off,csr_row,pm,mnArr,N);
  k_copy_u32<<<nbN,256,0,stream>>>(mis,cidx,N);
  big_scan(cidx,N,(unsigned*)(counters+1),ON);     // M = #MIS
  k_cl_map<<<nbN,256,0,stream>>>(rank,mis,cidx,map,counters+4,N);
  k_cl_cluster<<<nbN,256,0,stream>>>(mnArr,map,counters+4,cluster,N);
  k_gather_x<<<(N*(D/4)+255)/256,256,0,stream>>>((const float4*)x,(float4*)out,mis,cidx,N,D/4);

  // ---- coarsened edges: dynamic-packed pair sort (gated high passes) ----
  k_set_gates<<<1,1,0,stream>>>(counters);
  k_pair_key<<<nbE,256,0,stream>>>(row,col,cluster,attr,keyA,payA,counters,E);
  {
    unsigned long long *ki=keyA,*ko=keyB; unsigned *pi=payA,*po=payB;
    for (int pass=0; pass<4; ++pass){
      int shift = pass*9;
      const int* g = counters + 32 + pass;
      k_radix_hist<unsigned long long,RTILE><<<Be,256,0,stream>>>(ki,E,shift,ghist,Be,g);
      big_scan(ghist,512*Be,nullptr,g);
      k_radix_scatter<unsigned long long,RTILE><<<Be,256,0,stream>>>(ki,pi,ko,po,E,shift,ghist,Be,g);
      unsigned long long* tk=ki; ki=ko; ko=tk; unsigned* tp=pi; pi=po; po=tp;
    }
    // after even # of passes result is back in keyA/payA
    k_flags<<<nbE,256,0,stream>>>(keyA,scanA,scanB,counters,E);
    big_scan(scanA,E,(unsigned*)(counters+2),ON);   // group ids
    big_scan(scanB,E,(unsigned*)(counters+3),ON);   // E'
    k_acc_seg<<<nbE,256,0,stream>>>(keyA,payA,scanA,vals,E);
    k_write_edges<<<nbE,256,0,stream>>>(keyA,scanA,scanB,vals,out,counters,E,D);
  }
  k_write_nodes<<<nbN,256,0,stream>>>(cluster,mis,score,out,counters,N,D);
}